// Round 3
// baseline (184.868 us; speedup 1.0000x reference)
//
#include <hip/hip_runtime.h>
#include <math.h>

// Net_90434831385322: z = A + span*sigmoid(relu((x-A)/span @ W1 + b1) @ W2 + b2)
// BATCH=4194304, OBS=4, HID=64, ACT=4, all fp32.
//
// R6: MOVE THE MATMUL TO THE MATRIX PIPE. R3/R4/R5 (scalar fp32, packed-asm,
//     SGPR-weights) ALL landed 67-77us: v_pk_fma_f32 does NOT double fp32
//     throughput on CDNA4 (157.3 TF peak = 1 FMA/lane/cycle, scalar rate;
//     the packed op issues over 4 cyc). 4.3 GFLOP / 157 TF = 27us floor and
//     we pay ~2.6x overhead on top -> fp32-VALU is a wall.
//
//     Plan: mfma_f32_16x16x32_bf16 with 2-term bf16 SPLIT (hi+lo; 3 product
//     terms) for ~fp32 accuracy (rel err ~2^-17; plain bf16/fp16 would fail:
//     x1=(x-A)/span reaches 333).
//     Layout tricks (zero cross-lane shuffles anywhere):
//      - Layer 1 swapped: h^T = mfma(A=W1'^T-split, B=x-split), so C cols
//        (=lane&15, m89-verified) carry the BATCH index.
//      - Layer 2's K-order is chosen to be exactly layer-1's C-register
//        order: hid(k=32m+8g+j) = 32m + 16*(j>>2) + 4g + (j&3). B2-frags
//        are then just the cvt_pk-packed h words; prep bakes the same
//        permutation into W2's A-frags. No transpose, no LDS, no permute.
//      - Input scale folded into W1'/b1' (prep); b1' enters as 2 extra
//        K-slots vs a constant-1.0 B column; b2 added in epilogue.
//     Per 16-row tile: ~111 VALU + 10 MFMA + 2 VMEM.

#define BATCH   4194304
#define HID     64
#define TPB     256
#define TILES   (BATCH / 16)              // 262144 16-row tiles
#define TPW     32                        // tiles per wave
#define NWAVES  (TILES / TPW)             // 8192 waves
#define NBLK    (NWAVES / 4)              // 2048 blocks (4 waves each)

typedef float  f32x4  __attribute__((ext_vector_type(4)));
typedef short  bf16x8 __attribute__((ext_vector_type(8)));
typedef unsigned int uint;
typedef uint   u32x4  __attribute__((ext_vector_type(4)));

// ws layout (dwords):
//   [0    .. 1023]  A1 frags: [tile T=0..3][lane 0..63][4 dwords]  (W1'^T split + b1')
//   [1024 .. 2047]  A2 frags: [f=0..3][lane][4 dwords]; f0,f1 = W2hi k-chunks 0,1;
//                                                      f2,f3 = W2lo k-chunks 0,1
//   [2048 .. 2051]  b2[0..3] (fp32 bits)
#define WS_A1   0
#define WS_A2   1024
#define WS_B2   2048

// fp32 -> bf16 RNE (prep side; values are far from overflow)
static __device__ __forceinline__ uint b16(float f) {
    uint u = __float_as_uint(f);
    return (u + 0x7FFFu + ((u >> 16) & 1u)) >> 16;
}
static __device__ __forceinline__ float b16f(uint h) {
    return __uint_as_float(h << 16);
}

// packed f32x2 -> bf16x2 (RNE), dst.lo = cvt(a), dst.hi = cvt(b)
static __device__ __forceinline__ uint cvtpk(float a, float b) {
    uint r;
    asm("v_cvt_pk_bf16_f32 %0, %1, %2" : "=v"(r) : "v"(a), "v"(b));
    return r;
}

__global__ __launch_bounds__(64)
void prep_kernel(const float* __restrict__ W1, const float* __restrict__ b1,
                 const float* __restrict__ W2, const float* __restrict__ b2,
                 uint* __restrict__ ws) {
    const float A_[4] = {0.001f, 0.02f, 0.05f, 0.001f};
    const float S_[4] = {0.003f, 0.03f, 0.15f, 0.003f};   // span = B - A
    const int l = threadIdx.x;            // lane 0..63
    const int g = l >> 4;                 // k-group
    const int i = l & 15;                 // A free index (hid-in-tile / act)

    // ---- A1 frags: A1[row=hid=16T+i, k=8g+j] ----
    // k0-3: W1hi[obs,hid]   (x-hi side)     k4-7: W1hi  (x-lo side)
    // k8-11: W1lo[obs,hid]  (x-hi side)     k12: b1hi, k13: b1lo (vs B=1.0)
    for (int T = 0; T < 4; ++T) {
        int hid = 16 * T + i;
        uint s8[8] = {0, 0, 0, 0, 0, 0, 0, 0};
        if (g < 2) {
            uint whi[4], wlo[4];
            #pragma unroll
            for (int k = 0; k < 4; ++k) {
                float w = W1[k * HID + hid] / S_[k];       // fold input scale
                whi[k] = b16(w);
                wlo[k] = b16(w - b16f(whi[k]));
            }
            if (g == 0) {
                #pragma unroll
                for (int k = 0; k < 4; ++k) { s8[k] = whi[k]; s8[4 + k] = whi[k]; }
            } else {
                float bb = b1[hid];
                #pragma unroll
                for (int k = 0; k < 4; ++k) bb -= (A_[k] / S_[k]) * W1[k * HID + hid];
                #pragma unroll
                for (int k = 0; k < 4; ++k) s8[k] = wlo[k];
                uint bh = b16(bb);
                s8[4] = bh;
                s8[5] = b16(bb - b16f(bh));
                // s8[6],s8[7] = 0  (k14,15 dead)
            }
        }
        #pragma unroll
        for (int d = 0; d < 4; ++d)
            ws[WS_A1 + (T * 64 + l) * 4 + d] = (s8[2 * d + 1] << 16) | (s8[2 * d] & 0xFFFFu);
    }

    // ---- A2 frags: A2[row=act=i, k=8g+j], hid(k) = 32c + 16*(j>>2) + 4g + (j&3) ----
    for (int f = 0; f < 4; ++f) {
        int  c  = f & 1;        // k-chunk (hid 0-31 / 32-63 within each term)
        bool lo = (f >= 2);
        uint s8[8];
        #pragma unroll
        for (int j = 0; j < 8; ++j) {
            int hid = 32 * c + 16 * (j >> 2) + 4 * g + (j & 3);
            uint v = 0;
            if (i < 4) {
                float w  = W2[hid * 4 + i];
                uint  wh = b16(w);
                v = lo ? b16(w - b16f(wh)) : wh;
            }
            s8[j] = v;
        }
        #pragma unroll
        for (int d = 0; d < 4; ++d)
            ws[WS_A2 + (f * 64 + l) * 4 + d] = (s8[2 * d + 1] << 16) | (s8[2 * d] & 0xFFFFu);
    }

    if (l < 4) ws[WS_B2 + l] = __float_as_uint(b2[l]);
}

__global__ __launch_bounds__(TPB, 4)
void mlp_kernel(const float* __restrict__ x, const uint* __restrict__ ws,
                float* __restrict__ out) {
    const int lane = threadIdx.x & 63;
    const int wv   = threadIdx.x >> 6;
    const int g    = lane >> 4;
    const int i    = lane & 15;

    const f32x4* __restrict__ x4   = (const f32x4*)x;
    f32x4* __restrict__       out4 = (f32x4*)out;
    const u32x4* __restrict__ wsv  = (const u32x4*)ws;

    // Preload weight fragments (loop-invariant; ~32 VGPRs).
    bf16x8 A1f[4], A2f[4];
    #pragma unroll
    for (int T = 0; T < 4; ++T) A1f[T] = __builtin_bit_cast(bf16x8, wsv[(WS_A1 / 4) + T * 64 + lane]);
    #pragma unroll
    for (int f = 0; f < 4; ++f) A2f[f] = __builtin_bit_cast(bf16x8, wsv[(WS_A2 / 4) + f * 64 + lane]);
    const float* wsf = (const float*)ws;
    const float b2c[4] = {wsf[WS_B2], wsf[WS_B2 + 1], wsf[WS_B2 + 2], wsf[WS_B2 + 3]};

    const float LA[4] = {0.001f, 0.02f, 0.05f, 0.001f};
    const float LS[4] = {0.003f, 0.03f, 0.15f, 0.003f};
    const bool  isg1  = (g == 1);

    const long wave_id = (long)blockIdx.x * 4 + wv;
    const long t0      = wave_id * TPW;

    // 1-ahead prefetch of this lane's x row (lanes replicate by i; cache-served).
    f32x4 xv = x4[t0 * 16 + i];

    for (int tt = 0; tt < TPW; ++tt) {
        const long t  = t0 + tt;
        const long tn = (tt == TPW - 1) ? t : t + 1;
        f32x4 xn = x4[tn * 16 + i];

        // ---- build B1 (x split): B1[k=8g+j, col=i] ----
        // g0: [xhi0-3, xlo0-3]; g1: [xhi0-3, 1,1, 0,0]; g2,3: don't-care (A1=0)
        uint xhi01 = cvtpk(xv.x, xv.y);
        uint xhi23 = cvtpk(xv.z, xv.w);
        float h0 = __uint_as_float(xhi01 << 16);
        float h1 = __uint_as_float(xhi01 & 0xFFFF0000u);
        float h2 = __uint_as_float(xhi23 << 16);
        float h3 = __uint_as_float(xhi23 & 0xFFFF0000u);
        uint xlo01 = cvtpk(xv.x - h0, xv.y - h1);
        uint xlo23 = cvtpk(xv.z - h2, xv.w - h3);
        uint w2s = isg1 ? 0x3F803F80u : xlo01;   // bf16(1.0) pair for b1 slots
        uint w3s = isg1 ? 0u          : xlo23;
        u32x4 bw = {xhi01, xhi23, w2s, w3s};
        bf16x8 B1 = __builtin_bit_cast(bf16x8, bw);

        // ---- layer 1: h^T[hid, batch] (4 hid-tiles) ----
        f32x4 h[4];
        #pragma unroll
        for (int T = 0; T < 4; ++T)
            h[T] = __builtin_amdgcn_mfma_f32_16x16x32_bf16(A1f[T], B1, (f32x4){0.f, 0.f, 0.f, 0.f}, 0, 0, 0);

        // ---- relu + split h into bf16 hi/lo packed words ----
        // Whi[2T+w] = pack(h[T].reg(2w), h[T].reg(2w+1)) == B2 word order.
        uint Whi[8], Wlo[8];
        #pragma unroll
        for (int T = 0; T < 4; ++T) {
            float r0 = fmaxf(h[T][0], 0.f), r1 = fmaxf(h[T][1], 0.f);
            float r2 = fmaxf(h[T][2], 0.f), r3 = fmaxf(h[T][3], 0.f);
            uint hh0 = cvtpk(r0, r1), hh1 = cvtpk(r2, r3);
            float f0 = __uint_as_float(hh0 << 16);
            float f1 = __uint_as_float(hh0 & 0xFFFF0000u);
            float f2 = __uint_as_float(hh1 << 16);
            float f3 = __uint_as_float(hh1 & 0xFFFF0000u);
            Whi[2 * T]     = hh0;
            Whi[2 * T + 1] = hh1;
            Wlo[2 * T]     = cvtpk(r0 - f0, r1 - f1);
            Wlo[2 * T + 1] = cvtpk(r2 - f2, r3 - f3);
        }
        u32x4 bh0 = {Whi[0], Whi[1], Whi[2], Whi[3]};
        u32x4 bh1 = {Whi[4], Whi[5], Whi[6], Whi[7]};
        u32x4 bl0 = {Wlo[0], Wlo[1], Wlo[2], Wlo[3]};
        u32x4 bl1 = {Wlo[4], Wlo[5], Wlo[6], Wlo[7]};
        bf16x8 Bhi0 = __builtin_bit_cast(bf16x8, bh0);
        bf16x8 Bhi1 = __builtin_bit_cast(bf16x8, bh1);
        bf16x8 Blo0 = __builtin_bit_cast(bf16x8, bl0);
        bf16x8 Blo1 = __builtin_bit_cast(bf16x8, bl1);

        // ---- layer 2: y^T[act, batch], 3 split terms x 2 hid-chunks ----
        f32x4 C2 = {0.f, 0.f, 0.f, 0.f};
        C2 = __builtin_amdgcn_mfma_f32_16x16x32_bf16(A2f[0], Bhi0, C2, 0, 0, 0); // whi*hhi
        C2 = __builtin_amdgcn_mfma_f32_16x16x32_bf16(A2f[1], Bhi1, C2, 0, 0, 0);
        C2 = __builtin_amdgcn_mfma_f32_16x16x32_bf16(A2f[0], Blo0, C2, 0, 0, 0); // whi*hlo
        C2 = __builtin_amdgcn_mfma_f32_16x16x32_bf16(A2f[1], Blo1, C2, 0, 0, 0);
        C2 = __builtin_amdgcn_mfma_f32_16x16x32_bf16(A2f[2], Bhi0, C2, 0, 0, 0); // wlo*hhi
        C2 = __builtin_amdgcn_mfma_f32_16x16x32_bf16(A2f[3], Bhi1, C2, 0, 0, 0);

        // ---- epilogue: z = A + S*sigmoid(y+b2); valid rows live in g==0 lanes ----
        f32x4 z;
        #pragma unroll
        for (int c = 0; c < 4; ++c) {
            float y = C2[c] + b2c[c];
            float e = __expf(-y);
            z[c] = fmaf(LS[c], __builtin_amdgcn_rcpf(1.0f + e), LA[c]);
        }
        if (g == 0) out4[t * 16 + i] = z;

        xv = xn;
    }
}

extern "C" void kernel_launch(void* const* d_in, const int* in_sizes, int n_in,
                              void* d_out, int out_size, void* d_ws, size_t ws_size,
                              hipStream_t stream) {
    const float* x  = (const float*)d_in[0];
    const float* W1 = (const float*)d_in[1];
    const float* b1 = (const float*)d_in[2];
    const float* W2 = (const float*)d_in[3];
    const float* b2 = (const float*)d_in[4];
    float* out = (float*)d_out;
    uint*  ws  = (uint*)d_ws;

    prep_kernel<<<1, 64, 0, stream>>>(W1, b1, W2, b2, ws);
    mlp_kernel<<<NBLK, TPB, 0, stream>>>(x, ws, out);
}

// Round 4
// 178.620 us; speedup vs baseline: 1.0350x; 1.0350x over previous
//
#include <hip/hip_runtime.h>
#include <math.h>

// Net_90434831385322: z = A + span*sigmoid(relu((x-A)/span @ W1 + b1) @ W2 + b2)
// BATCH=4194304, OBS=4, HID=64, ACT=4, all fp32.
//
// R7: R6 (MFMA, 3-term bf16 split, shuffle-free layout) with the marshaling
//     fixed. R6 post-mortem: VALU busy 60us vs ~29us static -> VGPR_Count=36
//     proves frags/accumulators were AGPR-parked under launch_bounds(256,4),
//     paying v_accvgpr_read/write VALU traffic on every element touch.
//     Fixes:
//      (1) __launch_bounds__(256) only -- no occupancy floor, no AGPR motive.
//      (2) truncation splits: hi-pack = v_perm_b32 of two f32 (1 op/pair),
//          hi-as-f32 = v_and (independent), lo = exact sub, lo-pack = 1
//          cvtpk/pair. Shorter chains, cvtpk/tile 20 -> 10 (m240 hedge).
//          Residual 2^-17 (was 2^-18): absmax headroom covers (R6 pinned at
//          the 2^-10 comparison quantum, same as pure-fp32 rounds).
//      (3) TPW 16, 4096 blocks for scheduler backfill (Occ was 45%).
//     MFMA pipe floor ~18-20us (matches R6 MfmaUtil), VALU target ~30us,
//     overlapped -> ~40-55us mlp.

#define BATCH   4194304
#define HID     64
#define TPB     256
#define TILES   (BATCH / 16)              // 262144 16-row tiles
#define TPW     16                        // tiles per wave
#define NWAVES  (TILES / TPW)             // 16384 waves
#define NBLK    (NWAVES / 4)              // 4096 blocks (4 waves each)

typedef float  f32x4  __attribute__((ext_vector_type(4)));
typedef short  bf16x8 __attribute__((ext_vector_type(8)));
typedef unsigned int uint;
typedef uint   u32x4  __attribute__((ext_vector_type(4)));

// ws layout (dwords):
//   [0    .. 1023]  A1 frags: [tile T=0..3][lane 0..63][4 dwords]  (W1'^T split + b1')
//   [1024 .. 2047]  A2 frags: [f=0..3][lane][4 dwords]; f0,f1 = W2hi k-chunks 0,1;
//                                                      f2,f3 = W2lo k-chunks 0,1
//   [2048 .. 2051]  b2[0..3] (fp32 bits)
#define WS_A1   0
#define WS_A2   1024
#define WS_B2   2048

// fp32 -> bf16 RNE (prep side)
static __device__ __forceinline__ uint b16(float f) {
    uint u = __float_as_uint(f);
    return (u + 0x7FFFu + ((u >> 16) & 1u)) >> 16;
}
static __device__ __forceinline__ float b16f(uint h) {
    return __uint_as_float(h << 16);
}

// packed f32x2 -> bf16x2 (RNE), dst.lo = cvt(a), dst.hi = cvt(b)
static __device__ __forceinline__ uint cvtpk(float a, float b) {
    uint r;
    asm("v_cvt_pk_bf16_f32 %0, %1, %2" : "=v"(r) : "v"(a), "v"(b));
    return r;
}

// packed truncated-bf16 pair from two f32: {hi16(b), hi16(a)} -- one v_perm_b32
#define PERM_SEL 0x07060302u
static __device__ __forceinline__ uint trunc_pk(float a, float b) {
    return __builtin_amdgcn_perm(__float_as_uint(b), __float_as_uint(a), PERM_SEL);
}

__global__ __launch_bounds__(64)
void prep_kernel(const float* __restrict__ W1, const float* __restrict__ b1,
                 const float* __restrict__ W2, const float* __restrict__ b2,
                 uint* __restrict__ ws) {
    const float A_[4] = {0.001f, 0.02f, 0.05f, 0.001f};
    const float S_[4] = {0.003f, 0.03f, 0.15f, 0.003f};   // span = B - A
    const int l = threadIdx.x;            // lane 0..63
    const int g = l >> 4;                 // k-group
    const int i = l & 15;                 // A free index (hid-in-tile / act)

    // ---- A1 frags: A1[row=hid=16T+i, k=8g+j] ----
    // k0-3: W1hi (vs x-hi)   k4-7: W1hi (vs x-lo)
    // k8-11: W1lo (vs x-hi)  k12: b1hi, k13: b1lo (vs B=1.0), k14-15: 0
    for (int T = 0; T < 4; ++T) {
        int hid = 16 * T + i;
        uint s8[8] = {0, 0, 0, 0, 0, 0, 0, 0};
        if (g < 2) {
            uint whi[4], wlo[4];
            #pragma unroll
            for (int k = 0; k < 4; ++k) {
                float w = W1[k * HID + hid] / S_[k];       // fold input scale
                whi[k] = b16(w);
                wlo[k] = b16(w - b16f(whi[k]));
            }
            if (g == 0) {
                #pragma unroll
                for (int k = 0; k < 4; ++k) { s8[k] = whi[k]; s8[4 + k] = whi[k]; }
            } else {
                float bb = b1[hid];
                #pragma unroll
                for (int k = 0; k < 4; ++k) bb -= (A_[k] / S_[k]) * W1[k * HID + hid];
                #pragma unroll
                for (int k = 0; k < 4; ++k) s8[k] = wlo[k];
                uint bh = b16(bb);
                s8[4] = bh;
                s8[5] = b16(bb - b16f(bh));
            }
        }
        #pragma unroll
        for (int d = 0; d < 4; ++d)
            ws[WS_A1 + (T * 64 + l) * 4 + d] = (s8[2 * d + 1] << 16) | (s8[2 * d] & 0xFFFFu);
    }

    // ---- A2 frags: A2[row=act=i, k=8g+j], hid(k) = 32c + 16*(j>>2) + 4g + (j&3) ----
    for (int f = 0; f < 4; ++f) {
        int  c  = f & 1;
        bool lo = (f >= 2);
        uint s8[8];
        #pragma unroll
        for (int j = 0; j < 8; ++j) {
            int hid = 32 * c + 16 * (j >> 2) + 4 * g + (j & 3);
            uint v = 0;
            if (i < 4) {
                float w  = W2[hid * 4 + i];
                uint  wh = b16(w);
                v = lo ? b16(w - b16f(wh)) : wh;
            }
            s8[j] = v;
        }
        #pragma unroll
        for (int d = 0; d < 4; ++d)
            ws[WS_A2 + (f * 64 + l) * 4 + d] = (s8[2 * d + 1] << 16) | (s8[2 * d] & 0xFFFFu);
    }

    if (l < 4) ws[WS_B2 + l] = __float_as_uint(b2[l]);
}

__global__ __launch_bounds__(TPB)
void mlp_kernel(const float* __restrict__ x, const uint* __restrict__ ws,
                float* __restrict__ out) {
    const int lane = threadIdx.x & 63;
    const int wv   = threadIdx.x >> 6;
    const int g    = lane >> 4;
    const int i    = lane & 15;

    const f32x4* __restrict__ x4   = (const f32x4*)x;
    f32x4* __restrict__       out4 = (f32x4*)out;
    const u32x4* __restrict__ wsv  = (const u32x4*)ws;

    // Preload weight fragments (loop-invariant; 32 VGPRs, arch regs).
    bf16x8 A1f[4], A2f[4];
    #pragma unroll
    for (int T = 0; T < 4; ++T) A1f[T] = __builtin_bit_cast(bf16x8, wsv[(WS_A1 / 4) + T * 64 + lane]);
    #pragma unroll
    for (int f = 0; f < 4; ++f) A2f[f] = __builtin_bit_cast(bf16x8, wsv[(WS_A2 / 4) + f * 64 + lane]);
    const float* wsf = (const float*)ws;
    const float b2c[4] = {wsf[WS_B2], wsf[WS_B2 + 1], wsf[WS_B2 + 2], wsf[WS_B2 + 3]};

    const float LA[4] = {0.001f, 0.02f, 0.05f, 0.001f};
    const float LS[4] = {0.003f, 0.03f, 0.15f, 0.003f};
    const bool  isg1  = (g == 1);

    const long wave_id = (long)blockIdx.x * 4 + wv;
    const long t0      = wave_id * TPW;

    // 1-ahead prefetch of this lane's x row.
    f32x4 xv = x4[t0 * 16 + i];

    for (int tt = 0; tt < TPW; ++tt) {
        const long t  = t0 + tt;
        const long tn = (tt == TPW - 1) ? t : t + 1;
        f32x4 xn = x4[tn * 16 + i];

        // ---- build B1 (x split, truncation-hi): B1[k=8g+j, col=i] ----
        // g0: [xhi0-3, xlo0-3]; g1: [xhi0-3, 1,1, 0,0]; g2,3: don't-care (A1=0)
        uint xhi01 = trunc_pk(xv.x, xv.y);                 // v_perm
        uint xhi23 = trunc_pk(xv.z, xv.w);
        float h0 = __uint_as_float(__float_as_uint(xv.x) & 0xFFFF0000u);
        float h1 = __uint_as_float(__float_as_uint(xv.y) & 0xFFFF0000u);
        float h2 = __uint_as_float(__float_as_uint(xv.z) & 0xFFFF0000u);
        float h3 = __uint_as_float(__float_as_uint(xv.w) & 0xFFFF0000u);
        uint xlo01 = cvtpk(xv.x - h0, xv.y - h1);
        uint xlo23 = cvtpk(xv.z - h2, xv.w - h3);
        uint w2s = isg1 ? 0x3F803F80u : xlo01;   // bf16(1.0) pair for b1 slots
        uint w3s = isg1 ? 0u          : xlo23;
        u32x4 bw = {xhi01, xhi23, w2s, w3s};
        bf16x8 B1 = __builtin_bit_cast(bf16x8, bw);

        // ---- layer 1: h^T[hid, batch] (4 hid-tiles) ----
        f32x4 h[4];
        #pragma unroll
        for (int T = 0; T < 4; ++T)
            h[T] = __builtin_amdgcn_mfma_f32_16x16x32_bf16(A1f[T], B1, (f32x4){0.f, 0.f, 0.f, 0.f}, 0, 0, 0);

        // ---- relu + truncation split of h ----
        // Whi[2T+w] = trunc-pack(h pair) via v_perm; lo exact sub + cvtpk.
        uint Whi[8], Wlo[8];
        #pragma unroll
        for (int T = 0; T < 4; ++T) {
            float r0 = fmaxf(h[T][0], 0.f), r1 = fmaxf(h[T][1], 0.f);
            float r2 = fmaxf(h[T][2], 0.f), r3 = fmaxf(h[T][3], 0.f);
            Whi[2 * T]     = trunc_pk(r0, r1);
            Whi[2 * T + 1] = trunc_pk(r2, r3);
            float f0 = __uint_as_float(__float_as_uint(r0) & 0xFFFF0000u);
            float f1 = __uint_as_float(__float_as_uint(r1) & 0xFFFF0000u);
            float f2 = __uint_as_float(__float_as_uint(r2) & 0xFFFF0000u);
            float f3 = __uint_as_float(__float_as_uint(r3) & 0xFFFF0000u);
            Wlo[2 * T]     = cvtpk(r0 - f0, r1 - f1);
            Wlo[2 * T + 1] = cvtpk(r2 - f2, r3 - f3);
        }
        u32x4 bh0 = {Whi[0], Whi[1], Whi[2], Whi[3]};
        u32x4 bh1 = {Whi[4], Whi[5], Whi[6], Whi[7]};
        u32x4 bl0 = {Wlo[0], Wlo[1], Wlo[2], Wlo[3]};
        u32x4 bl1 = {Wlo[4], Wlo[5], Wlo[6], Wlo[7]};
        bf16x8 Bhi0 = __builtin_bit_cast(bf16x8, bh0);
        bf16x8 Bhi1 = __builtin_bit_cast(bf16x8, bh1);
        bf16x8 Blo0 = __builtin_bit_cast(bf16x8, bl0);
        bf16x8 Blo1 = __builtin_bit_cast(bf16x8, bl1);

        // ---- layer 2: y^T[act, batch], 3 split terms x 2 hid-chunks ----
        f32x4 C2 = {0.f, 0.f, 0.f, 0.f};
        C2 = __builtin_amdgcn_mfma_f32_16x16x32_bf16(A2f[0], Bhi0, C2, 0, 0, 0); // whi*hhi
        C2 = __builtin_amdgcn_mfma_f32_16x16x32_bf16(A2f[1], Bhi1, C2, 0, 0, 0);
        C2 = __builtin_amdgcn_mfma_f32_16x16x32_bf16(A2f[0], Blo0, C2, 0, 0, 0); // whi*hlo
        C2 = __builtin_amdgcn_mfma_f32_16x16x32_bf16(A2f[1], Blo1, C2, 0, 0, 0);
        C2 = __builtin_amdgcn_mfma_f32_16x16x32_bf16(A2f[2], Bhi0, C2, 0, 0, 0); // wlo*hhi
        C2 = __builtin_amdgcn_mfma_f32_16x16x32_bf16(A2f[3], Bhi1, C2, 0, 0, 0);

        // ---- epilogue: z = A + S*sigmoid(y+b2); valid rows in g==0 lanes ----
        f32x4 z;
        #pragma unroll
        for (int c = 0; c < 4; ++c) {
            float y = C2[c] + b2c[c];
            float e = __expf(-y);
            z[c] = fmaf(LS[c], __builtin_amdgcn_rcpf(1.0f + e), LA[c]);
        }
        if (g == 0) out4[t * 16 + i] = z;

        xv = xn;
    }
}

extern "C" void kernel_launch(void* const* d_in, const int* in_sizes, int n_in,
                              void* d_out, int out_size, void* d_ws, size_t ws_size,
                              hipStream_t stream) {
    const float* x  = (const float*)d_in[0];
    const float* W1 = (const float*)d_in[1];
    const float* b1 = (const float*)d_in[2];
    const float* W2 = (const float*)d_in[3];
    const float* b2 = (const float*)d_in[4];
    float* out = (float*)d_out;
    uint*  ws  = (uint*)d_ws;

    prep_kernel<<<1, 64, 0, stream>>>(W1, b1, W2, b2, ws);
    mlp_kernel<<<NBLK, TPB, 0, stream>>>(x, ws, out);
}

// Round 5
// 178.488 us; speedup vs baseline: 1.0357x; 1.0007x over previous
//
#include <hip/hip_runtime.h>
#include <math.h>

// Net_90434831385322: z = A + span*sigmoid(relu((x-A)/span @ W1 + b1) @ W2 + b2)
// BATCH=4194304, OBS=4, HID=64, ACT=4, all fp32.
//
// R8: kill the AGPR round-trips. Calibrated cycle model (R3 scalar anchor:
//     2.8 cyc/VALU-instr) says R7 executes ~219 instrs/tile vs ~110 static;
//     VGPR_Count=36 (impossible for 32 live frag regs) => MFMA results live
//     in AGPRs and every VALU touch pays v_accvgpr_read/write.
//     Fixes:
//      (1) PIN(v): empty asm "+v" on every MFMA result -> forces arch-VGPR
//          class (gfx950 MFMA writes VGPRs natively; unified RF) -> zero
//          copies, whole dataflow VGPR-resident.
//      (2) fold -log2e into W2/b2 (prep) -> C2 = -y*log2e; sigmoid =
//          1/(1+exp2(C2)) via v_exp_f32; b2'' enters as MFMA C-init.
//          Epilogue 22 -> 16 instrs/tile.
//      (3) 2-tile unroll (TPW=8, 8192 blocks): two independent MFMA chains
//          in flight to cover MFMA latency.
//     Layout (verified R6/R7, absmax == fp32 rounds): swapped L1, L2 K-order
//     == L1 C-order, 3-term bf16 split, shuffle-free.

#define BATCH   4194304
#define HID     64
#define TPB     256
#define TILES   (BATCH / 16)              // 262144 16-row tiles
#define TPW     8                         // tiles per wave
#define NWAVES  (TILES / TPW)             // 32768 waves
#define NBLK    (NWAVES / 4)              // 8192 blocks (4 waves each)

typedef float  f32x4  __attribute__((ext_vector_type(4)));
typedef short  bf16x8 __attribute__((ext_vector_type(8)));
typedef unsigned int uint;
typedef uint   u32x4  __attribute__((ext_vector_type(4)));

// ws layout (dwords):
//   [0    .. 1023]  A1 frags: [tile T=0..3][lane 0..63][4 dwords]  (W1'^T split + b1')
//   [1024 .. 2047]  A2 frags: [f=0..3][lane][4 dwords]; f0,f1 = W2hi'' k-chunks 0,1;
//                                                      f2,f3 = W2lo'' k-chunks 0,1
//                   (W2'' = -log2e * W2)
//   [2048 .. 2051]  b2'' = -log2e * b2 (fp32 bits)
#define WS_A1   0
#define WS_A2   1024
#define WS_B2   2048

// Force a value into the arch-VGPR register class (zero instructions if the
// allocator complies; prevents AGPR parking + accvgpr_read/write traffic).
#define PIN(v) asm("" : "+v"(v))

// fp32 -> bf16 RNE (prep side)
static __device__ __forceinline__ uint b16(float f) {
    uint u = __float_as_uint(f);
    return (u + 0x7FFFu + ((u >> 16) & 1u)) >> 16;
}
static __device__ __forceinline__ float b16f(uint h) {
    return __uint_as_float(h << 16);
}

// packed f32x2 -> bf16x2 (RNE), dst.lo = cvt(a), dst.hi = cvt(b)
static __device__ __forceinline__ uint cvtpk(float a, float b) {
    uint r;
    asm("v_cvt_pk_bf16_f32 %0, %1, %2" : "=v"(r) : "v"(a), "v"(b));
    return r;
}

// packed truncated-bf16 pair from two f32: {hi16(b), hi16(a)} -- one v_perm_b32
#define PERM_SEL 0x07060302u
static __device__ __forceinline__ uint trunc_pk(float a, float b) {
    return __builtin_amdgcn_perm(__float_as_uint(b), __float_as_uint(a), PERM_SEL);
}

static __device__ __forceinline__ float exp2_fast(float a) {
#if __has_builtin(__builtin_amdgcn_exp2f)
    return __builtin_amdgcn_exp2f(a);
#else
    return exp2f(a);
#endif
}

__global__ __launch_bounds__(64)
void prep_kernel(const float* __restrict__ W1, const float* __restrict__ b1,
                 const float* __restrict__ W2, const float* __restrict__ b2,
                 uint* __restrict__ ws) {
    const float A_[4] = {0.001f, 0.02f, 0.05f, 0.001f};
    const float S_[4] = {0.003f, 0.03f, 0.15f, 0.003f};   // span = B - A
    const float NL2E  = -1.442695040888963f;              // -log2(e)
    const int l = threadIdx.x;            // lane 0..63
    const int g = l >> 4;                 // k-group
    const int i = l & 15;                 // A free index (hid-in-tile / act)

    // ---- A1 frags: A1[row=hid=16T+i, k=8g+j] ----
    // k0-3: W1hi (vs x-hi)   k4-7: W1hi (vs x-lo)
    // k8-11: W1lo (vs x-hi)  k12: b1hi, k13: b1lo (vs B=1.0), k14-15: 0
    for (int T = 0; T < 4; ++T) {
        int hid = 16 * T + i;
        uint s8[8] = {0, 0, 0, 0, 0, 0, 0, 0};
        if (g < 2) {
            uint whi[4], wlo[4];
            #pragma unroll
            for (int k = 0; k < 4; ++k) {
                float w = W1[k * HID + hid] / S_[k];       // fold input scale
                whi[k] = b16(w);
                wlo[k] = b16(w - b16f(whi[k]));
            }
            if (g == 0) {
                #pragma unroll
                for (int k = 0; k < 4; ++k) { s8[k] = whi[k]; s8[4 + k] = whi[k]; }
            } else {
                float bb = b1[hid];
                #pragma unroll
                for (int k = 0; k < 4; ++k) bb -= (A_[k] / S_[k]) * W1[k * HID + hid];
                #pragma unroll
                for (int k = 0; k < 4; ++k) s8[k] = wlo[k];
                uint bh = b16(bb);
                s8[4] = bh;
                s8[5] = b16(bb - b16f(bh));
            }
        }
        #pragma unroll
        for (int d = 0; d < 4; ++d)
            ws[WS_A1 + (T * 64 + l) * 4 + d] = (s8[2 * d + 1] << 16) | (s8[2 * d] & 0xFFFFu);
    }

    // ---- A2 frags: A2[row=act=i, k=8g+j], hid(k) = 32c + 16*(j>>2) + 4g + (j&3) ----
    // W2'' = -log2e * W2  (so C2 = -y*log2e and sigmoid = 1/(1+exp2(C2)))
    for (int f = 0; f < 4; ++f) {
        int  c  = f & 1;
        bool lo = (f >= 2);
        uint s8[8];
        #pragma unroll
        for (int j = 0; j < 8; ++j) {
            int hid = 32 * c + 16 * (j >> 2) + 4 * g + (j & 3);
            uint v = 0;
            if (i < 4) {
                float w  = W2[hid * 4 + i] * NL2E;
                uint  wh = b16(w);
                v = lo ? b16(w - b16f(wh)) : wh;
            }
            s8[j] = v;
        }
        #pragma unroll
        for (int d = 0; d < 4; ++d)
            ws[WS_A2 + (f * 64 + l) * 4 + d] = (s8[2 * d + 1] << 16) | (s8[2 * d] & 0xFFFFu);
    }

    if (l < 4) ws[WS_B2 + l] = __float_as_uint(b2[l] * NL2E);
}

// One 16-row tile: x(f32x4) -> z(f32x4). All MFMA results PINned to VGPRs.
static __device__ __forceinline__ f32x4 tile_eval(f32x4 xv,
                                                  const bf16x8* __restrict__ A1f,
                                                  const bf16x8* __restrict__ A2f,
                                                  f32x4 Cinit, bool isg1) {
    // ---- build B1 (x split, truncation-hi): B1[k=8g+j, col=i] ----
    uint xhi01 = trunc_pk(xv.x, xv.y);
    uint xhi23 = trunc_pk(xv.z, xv.w);
    float h0 = __uint_as_float(__float_as_uint(xv.x) & 0xFFFF0000u);
    float h1 = __uint_as_float(__float_as_uint(xv.y) & 0xFFFF0000u);
    float h2 = __uint_as_float(__float_as_uint(xv.z) & 0xFFFF0000u);
    float h3 = __uint_as_float(__float_as_uint(xv.w) & 0xFFFF0000u);
    uint xlo01 = cvtpk(xv.x - h0, xv.y - h1);
    uint xlo23 = cvtpk(xv.z - h2, xv.w - h3);
    uint w2s = isg1 ? 0x3F803F80u : xlo01;   // bf16(1.0) pair for b1 slots
    uint w3s = isg1 ? 0u          : xlo23;
    u32x4 bw = {xhi01, xhi23, w2s, w3s};
    bf16x8 B1 = __builtin_bit_cast(bf16x8, bw);

    // ---- layer 1: h^T[hid, batch] (4 hid-tiles) ----
    f32x4 h[4];
    #pragma unroll
    for (int T = 0; T < 4; ++T) {
        h[T] = __builtin_amdgcn_mfma_f32_16x16x32_bf16(A1f[T], B1, (f32x4){0.f, 0.f, 0.f, 0.f}, 0, 0, 0);
        PIN(h[T]);
    }

    // ---- relu + truncation split of h ----
    uint Whi[8], Wlo[8];
    #pragma unroll
    for (int T = 0; T < 4; ++T) {
        float r0 = fmaxf(h[T][0], 0.f), r1 = fmaxf(h[T][1], 0.f);
        float r2 = fmaxf(h[T][2], 0.f), r3 = fmaxf(h[T][3], 0.f);
        Whi[2 * T]     = trunc_pk(r0, r1);
        Whi[2 * T + 1] = trunc_pk(r2, r3);
        float f0 = __uint_as_float(__float_as_uint(r0) & 0xFFFF0000u);
        float f1 = __uint_as_float(__float_as_uint(r1) & 0xFFFF0000u);
        float f2 = __uint_as_float(__float_as_uint(r2) & 0xFFFF0000u);
        float f3 = __uint_as_float(__float_as_uint(r3) & 0xFFFF0000u);
        Wlo[2 * T]     = cvtpk(r0 - f0, r1 - f1);
        Wlo[2 * T + 1] = cvtpk(r2 - f2, r3 - f3);
    }
    u32x4 bh0 = {Whi[0], Whi[1], Whi[2], Whi[3]};
    u32x4 bh1 = {Whi[4], Whi[5], Whi[6], Whi[7]};
    u32x4 bl0 = {Wlo[0], Wlo[1], Wlo[2], Wlo[3]};
    u32x4 bl1 = {Wlo[4], Wlo[5], Wlo[6], Wlo[7]};
    bf16x8 Bhi0 = __builtin_bit_cast(bf16x8, bh0);
    bf16x8 Bhi1 = __builtin_bit_cast(bf16x8, bh1);
    bf16x8 Blo0 = __builtin_bit_cast(bf16x8, bl0);
    bf16x8 Blo1 = __builtin_bit_cast(bf16x8, bl1);

    // ---- layer 2: C2 = -log2e*(y) with b2'' as C-init ----
    f32x4 C = Cinit;
    C = __builtin_amdgcn_mfma_f32_16x16x32_bf16(A2f[0], Bhi0, C, 0, 0, 0); PIN(C);
    C = __builtin_amdgcn_mfma_f32_16x16x32_bf16(A2f[1], Bhi1, C, 0, 0, 0); PIN(C);
    C = __builtin_amdgcn_mfma_f32_16x16x32_bf16(A2f[0], Blo0, C, 0, 0, 0); PIN(C);
    C = __builtin_amdgcn_mfma_f32_16x16x32_bf16(A2f[1], Blo1, C, 0, 0, 0); PIN(C);
    C = __builtin_amdgcn_mfma_f32_16x16x32_bf16(A2f[2], Bhi0, C, 0, 0, 0); PIN(C);
    C = __builtin_amdgcn_mfma_f32_16x16x32_bf16(A2f[3], Bhi1, C, 0, 0, 0); PIN(C);

    // ---- epilogue: z = A + S * 1/(1 + 2^C) ----
    const float LA[4] = {0.001f, 0.02f, 0.05f, 0.001f};
    const float LS[4] = {0.003f, 0.03f, 0.15f, 0.003f};
    f32x4 z;
    #pragma unroll
    for (int c = 0; c < 4; ++c) {
        float e = exp2_fast(C[c]);
        z[c] = fmaf(LS[c], __builtin_amdgcn_rcpf(1.0f + e), LA[c]);
    }
    return z;
}

__global__ __launch_bounds__(TPB)
void mlp_kernel(const float* __restrict__ x, const uint* __restrict__ ws,
                float* __restrict__ out) {
    const int lane = threadIdx.x & 63;
    const int wv   = threadIdx.x >> 6;
    const int g    = lane >> 4;
    const int i    = lane & 15;

    const f32x4* __restrict__ x4   = (const f32x4*)x;
    f32x4* __restrict__       out4 = (f32x4*)out;
    const u32x4* __restrict__ wsv  = (const u32x4*)ws;

    // Preload weight fragments (loop-invariant), pinned to arch VGPRs.
    bf16x8 A1f[4], A2f[4];
    #pragma unroll
    for (int T = 0; T < 4; ++T) {
        A1f[T] = __builtin_bit_cast(bf16x8, wsv[(WS_A1 / 4) + T * 64 + lane]);
        PIN(A1f[T]);
    }
    #pragma unroll
    for (int f = 0; f < 4; ++f) {
        A2f[f] = __builtin_bit_cast(bf16x8, wsv[(WS_A2 / 4) + f * 64 + lane]);
        PIN(A2f[f]);
    }
    const float* wsf = (const float*)ws;
    f32x4 Cinit = {wsf[WS_B2], wsf[WS_B2 + 1], wsf[WS_B2 + 2], wsf[WS_B2 + 3]};
    PIN(Cinit);

    const bool isg1 = (g == 1);
    const long wave_id = (long)blockIdx.x * 4 + wv;
    const long t0      = wave_id * TPW;

    // Two tile streams in flight, 1-pair-ahead prefetch.
    f32x4 xv0 = x4[(t0 + 0) * 16 + i];
    f32x4 xv1 = x4[(t0 + 1) * 16 + i];

    for (int tt = 0; tt < TPW; tt += 2) {
        const long t  = t0 + tt;
        const long tn = (tt + 2 < TPW) ? (t + 2) : t;
        f32x4 xn0 = x4[tn * 16 + i];
        f32x4 xn1 = x4[(tn + 1) * 16 + i];

        f32x4 z0 = tile_eval(xv0, A1f, A2f, Cinit, isg1);
        f32x4 z1 = tile_eval(xv1, A1f, A2f, Cinit, isg1);

        if (g == 0) {
            out4[t * 16 + i]       = z0;
            out4[(t + 1) * 16 + i] = z1;
        }
        xv0 = xn0;
        xv1 = xn1;
    }
}

extern "C" void kernel_launch(void* const* d_in, const int* in_sizes, int n_in,
                              void* d_out, int out_size, void* d_ws, size_t ws_size,
                              hipStream_t stream) {
    const float* x  = (const float*)d_in[0];
    const float* W1 = (const float*)d_in[1];
    const float* b1 = (const float*)d_in[2];
    const float* W2 = (const float*)d_in[3];
    const float* b2 = (const float*)d_in[4];
    float* out = (float*)d_out;
    uint*  ws  = (uint*)d_ws;

    prep_kernel<<<1, 64, 0, stream>>>(W1, b1, W2, b2, ws);
    mlp_kernel<<<NBLK, TPB, 0, stream>>>(x, ws, out);
}

// Round 6
// 164.118 us; speedup vs baseline: 1.1264x; 1.0876x over previous
//
#include <hip/hip_runtime.h>
#include <math.h>

// Net_90434831385322: z = A + span*sigmoid(relu((x-A)/span @ W1 + b1) @ W2 + b2)
// BATCH=4194304, OBS=4, HID=64, ACT=4, all fp32.
//
// R9: R7 structure, scheduling fixed. Calibrated model now closes: R7 tile =
//     ~446 cyc marshaling-VALU (156 instr @ 2.87 eff) + 194 cyc MFMA (counted
//     in VALUBusy by the gfx94x-formula fallback) + ~170 cyc stalls. The
//     stalls come from the 6-deep serial L2 MFMA chain (~180 cyc latency) and
//     MFMA->VALU h-consumption at only ~4 waves/SIMD. R8's PIN was a copy
//     generator (VALUBusy 95%), not a fix.
//     Changes vs R7:
//      (1) NO PIN anywhere.
//      (2) exp2 fold kept (W2''=-log2e*W2, b2'' as MFMA C-init; validated R8).
//      (3) L2 = TWO independent 3-MFMA chains (Ca from b2'', Cb from 0,
//          C=Ca+Cb): halves serial MFMA latency, +4 v_add.
//      (4) 2-tile interleave per iteration: two independent MFMA DAGs hide
//          each other's latency (now without PIN pollution).
//      (5) __launch_bounds__(256,2): explicit 2-waves/EU floor (VGPR cap 256)
//          so the allocator stops occupancy-squeezing into AGPR-parking.
//      (6) prep parallelized 4x (256 threads) to cut the serial prefix.

#define BATCH   4194304
#define HID     64
#define TPB     256
#define TILES   (BATCH / 16)              // 262144 16-row tiles
#define TPW     8                         // tiles per wave
#define NWAVES  (TILES / TPW)             // 32768 waves
#define NBLK    (NWAVES / 4)              // 8192 blocks (4 waves each)

typedef float  f32x4  __attribute__((ext_vector_type(4)));
typedef short  bf16x8 __attribute__((ext_vector_type(8)));
typedef unsigned int uint;
typedef uint   u32x4  __attribute__((ext_vector_type(4)));

// ws layout (dwords):
//   [0    .. 1023]  A1 frags: [tile T=0..3][lane 0..63][4 dwords]  (W1'^T split + b1')
//   [1024 .. 2047]  A2 frags: [f=0..3][lane][4 dwords]; f0,f1 = W2hi'' k-chunks 0,1;
//                                                      f2,f3 = W2lo'' k-chunks 0,1
//                   (W2'' = -log2e * W2)
//   [2048 .. 2051]  b2'' = -log2e * b2 (fp32 bits)
#define WS_A1   0
#define WS_A2   1024
#define WS_B2   2048

// fp32 -> bf16 RNE (prep side)
static __device__ __forceinline__ uint b16(float f) {
    uint u = __float_as_uint(f);
    return (u + 0x7FFFu + ((u >> 16) & 1u)) >> 16;
}
static __device__ __forceinline__ float b16f(uint h) {
    return __uint_as_float(h << 16);
}

// packed f32x2 -> bf16x2 (RNE), dst.lo = cvt(a), dst.hi = cvt(b)
static __device__ __forceinline__ uint cvtpk(float a, float b) {
    uint r;
    asm("v_cvt_pk_bf16_f32 %0, %1, %2" : "=v"(r) : "v"(a), "v"(b));
    return r;
}

// packed truncated-bf16 pair from two f32: {hi16(b), hi16(a)} -- one v_perm_b32
#define PERM_SEL 0x07060302u
static __device__ __forceinline__ uint trunc_pk(float a, float b) {
    return __builtin_amdgcn_perm(__float_as_uint(b), __float_as_uint(a), PERM_SEL);
}

// deterministic raw 2^x
static __device__ __forceinline__ float exp2_fast(float a) {
    float r;
    asm("v_exp_f32 %0, %1" : "=v"(r) : "v"(a));
    return r;
}

__global__ __launch_bounds__(256)
void prep_kernel(const float* __restrict__ W1, const float* __restrict__ b1,
                 const float* __restrict__ W2, const float* __restrict__ b2,
                 uint* __restrict__ ws) {
    const float A_[4] = {0.001f, 0.02f, 0.05f, 0.001f};
    const float S_[4] = {0.003f, 0.03f, 0.15f, 0.003f};   // span = B - A
    const float NL2E  = -1.442695040888963f;              // -log2(e)
    const int tid = threadIdx.x;
    const int w = tid >> 6;               // 0..3: selects T (A1) and f (A2)
    const int l = tid & 63;               // lane 0..63
    const int g = l >> 4;                 // k-group
    const int i = l & 15;                 // A free index (hid-in-tile / act)

    // ---- A1 frag for T=w: A1[row=hid=16T+i, k=8g+j] ----
    // k0-3: W1hi (vs x-hi)   k4-7: W1hi (vs x-lo)
    // k8-11: W1lo (vs x-hi)  k12: b1hi, k13: b1lo (vs B=1.0), k14-15: 0
    {
        int hid = 16 * w + i;
        uint s8[8] = {0, 0, 0, 0, 0, 0, 0, 0};
        if (g < 2) {
            uint whi[4], wlo[4];
            #pragma unroll
            for (int k = 0; k < 4; ++k) {
                float wv = W1[k * HID + hid] / S_[k];      // fold input scale
                whi[k] = b16(wv);
                wlo[k] = b16(wv - b16f(whi[k]));
            }
            if (g == 0) {
                #pragma unroll
                for (int k = 0; k < 4; ++k) { s8[k] = whi[k]; s8[4 + k] = whi[k]; }
            } else {
                float bb = b1[hid];
                #pragma unroll
                for (int k = 0; k < 4; ++k) bb -= (A_[k] / S_[k]) * W1[k * HID + hid];
                #pragma unroll
                for (int k = 0; k < 4; ++k) s8[k] = wlo[k];
                uint bh = b16(bb);
                s8[4] = bh;
                s8[5] = b16(bb - b16f(bh));
            }
        }
        #pragma unroll
        for (int d = 0; d < 4; ++d)
            ws[WS_A1 + (w * 64 + l) * 4 + d] = (s8[2 * d + 1] << 16) | (s8[2 * d] & 0xFFFFu);
    }

    // ---- A2 frag for f=w: A2[row=act=i, k=8g+j], hid(k)=32c+16*(j>>2)+4g+(j&3) ----
    {
        int  c  = w & 1;
        bool lo = (w >= 2);
        uint s8[8];
        #pragma unroll
        for (int j = 0; j < 8; ++j) {
            int hid = 32 * c + 16 * (j >> 2) + 4 * g + (j & 3);
            uint v = 0;
            if (i < 4) {
                float wv = W2[hid * 4 + i] * NL2E;
                uint  wh = b16(wv);
                v = lo ? b16(wv - b16f(wh)) : wh;
            }
            s8[j] = v;
        }
        #pragma unroll
        for (int d = 0; d < 4; ++d)
            ws[WS_A2 + (w * 64 + l) * 4 + d] = (s8[2 * d + 1] << 16) | (s8[2 * d] & 0xFFFFu);
    }

    if (tid < 4) ws[WS_B2 + tid] = __float_as_uint(b2[tid] * NL2E);
}

// One 16-row tile: x(f32x4) -> z(f32x4). No register-class games.
static __device__ __forceinline__ f32x4 tile_eval(f32x4 xv,
                                                  const bf16x8* __restrict__ A1f,
                                                  const bf16x8* __restrict__ A2f,
                                                  f32x4 Cinit, bool isg1) {
    // ---- build B1 (x split, truncation-hi): B1[k=8g+j, col=i] ----
    uint xhi01 = trunc_pk(xv.x, xv.y);
    uint xhi23 = trunc_pk(xv.z, xv.w);
    float h0 = __uint_as_float(__float_as_uint(xv.x) & 0xFFFF0000u);
    float h1 = __uint_as_float(__float_as_uint(xv.y) & 0xFFFF0000u);
    float h2 = __uint_as_float(__float_as_uint(xv.z) & 0xFFFF0000u);
    float h3 = __uint_as_float(__float_as_uint(xv.w) & 0xFFFF0000u);
    uint xlo01 = cvtpk(xv.x - h0, xv.y - h1);
    uint xlo23 = cvtpk(xv.z - h2, xv.w - h3);
    uint w2s = isg1 ? 0x3F803F80u : xlo01;   // bf16(1.0) pair for b1 slots
    uint w3s = isg1 ? 0u          : xlo23;
    u32x4 bw = {xhi01, xhi23, w2s, w3s};
    bf16x8 B1 = __builtin_bit_cast(bf16x8, bw);

    // ---- layer 1: h^T[hid, batch] (4 hid-tiles, independent MFMAs) ----
    f32x4 h[4];
    #pragma unroll
    for (int T = 0; T < 4; ++T)
        h[T] = __builtin_amdgcn_mfma_f32_16x16x32_bf16(A1f[T], B1, (f32x4){0.f, 0.f, 0.f, 0.f}, 0, 0, 0);

    // ---- relu + truncation split of h ----
    uint Whi[8], Wlo[8];
    #pragma unroll
    for (int T = 0; T < 4; ++T) {
        float r0 = fmaxf(h[T][0], 0.f), r1 = fmaxf(h[T][1], 0.f);
        float r2 = fmaxf(h[T][2], 0.f), r3 = fmaxf(h[T][3], 0.f);
        Whi[2 * T]     = trunc_pk(r0, r1);
        Whi[2 * T + 1] = trunc_pk(r2, r3);
        float f0 = __uint_as_float(__float_as_uint(r0) & 0xFFFF0000u);
        float f1 = __uint_as_float(__float_as_uint(r1) & 0xFFFF0000u);
        float f2 = __uint_as_float(__float_as_uint(r2) & 0xFFFF0000u);
        float f3 = __uint_as_float(__float_as_uint(r3) & 0xFFFF0000u);
        Wlo[2 * T]     = cvtpk(r0 - f0, r1 - f1);
        Wlo[2 * T + 1] = cvtpk(r2 - f2, r3 - f3);
    }
    u32x4 bh0 = {Whi[0], Whi[1], Whi[2], Whi[3]};
    u32x4 bh1 = {Whi[4], Whi[5], Whi[6], Whi[7]};
    u32x4 bl0 = {Wlo[0], Wlo[1], Wlo[2], Wlo[3]};
    u32x4 bl1 = {Wlo[4], Wlo[5], Wlo[6], Wlo[7]};
    bf16x8 Bhi0 = __builtin_bit_cast(bf16x8, bh0);
    bf16x8 Bhi1 = __builtin_bit_cast(bf16x8, bh1);
    bf16x8 Blo0 = __builtin_bit_cast(bf16x8, bl0);
    bf16x8 Blo1 = __builtin_bit_cast(bf16x8, bl1);

    // ---- layer 2: two INDEPENDENT 3-MFMA chains (halved serial latency) ----
    f32x4 Ca = Cinit;                     // carries b2''
    f32x4 Cb = {0.f, 0.f, 0.f, 0.f};
    Ca = __builtin_amdgcn_mfma_f32_16x16x32_bf16(A2f[0], Bhi0, Ca, 0, 0, 0);
    Cb = __builtin_amdgcn_mfma_f32_16x16x32_bf16(A2f[1], Bhi1, Cb, 0, 0, 0);
    Ca = __builtin_amdgcn_mfma_f32_16x16x32_bf16(A2f[0], Blo0, Ca, 0, 0, 0);
    Cb = __builtin_amdgcn_mfma_f32_16x16x32_bf16(A2f[1], Blo1, Cb, 0, 0, 0);
    Ca = __builtin_amdgcn_mfma_f32_16x16x32_bf16(A2f[2], Bhi0, Ca, 0, 0, 0);
    Cb = __builtin_amdgcn_mfma_f32_16x16x32_bf16(A2f[3], Bhi1, Cb, 0, 0, 0);
    f32x4 C = Ca + Cb;                    // C = -log2e*y

    // ---- epilogue: z = A + S * 1/(1 + 2^C) ----
    const float LA[4] = {0.001f, 0.02f, 0.05f, 0.001f};
    const float LS[4] = {0.003f, 0.03f, 0.15f, 0.003f};
    f32x4 z;
    #pragma unroll
    for (int c = 0; c < 4; ++c) {
        float e = exp2_fast(C[c]);
        z[c] = fmaf(LS[c], __builtin_amdgcn_rcpf(1.0f + e), LA[c]);
    }
    return z;
}

__global__ __launch_bounds__(TPB, 2)
void mlp_kernel(const float* __restrict__ x, const uint* __restrict__ ws,
                float* __restrict__ out) {
    const int lane = threadIdx.x & 63;
    const int wv   = threadIdx.x >> 6;
    const int g    = lane >> 4;
    const int i    = lane & 15;

    const f32x4* __restrict__ x4   = (const f32x4*)x;
    f32x4* __restrict__       out4 = (f32x4*)out;
    const u32x4* __restrict__ wsv  = (const u32x4*)ws;

    // Preload weight fragments (loop-invariant).
    bf16x8 A1f[4], A2f[4];
    #pragma unroll
    for (int T = 0; T < 4; ++T) A1f[T] = __builtin_bit_cast(bf16x8, wsv[(WS_A1 / 4) + T * 64 + lane]);
    #pragma unroll
    for (int f = 0; f < 4; ++f) A2f[f] = __builtin_bit_cast(bf16x8, wsv[(WS_A2 / 4) + f * 64 + lane]);
    const float* wsf = (const float*)ws;
    f32x4 Cinit = {wsf[WS_B2], wsf[WS_B2 + 1], wsf[WS_B2 + 2], wsf[WS_B2 + 3]};

    const bool isg1 = (g == 1);
    const long wave_id = (long)blockIdx.x * 4 + wv;
    const long t0      = wave_id * TPW;

    // Two independent tile streams in flight, 1-pair-ahead prefetch.
    f32x4 xv0 = x4[(t0 + 0) * 16 + i];
    f32x4 xv1 = x4[(t0 + 1) * 16 + i];

    #pragma unroll
    for (int tt = 0; tt < TPW; tt += 2) {
        const long t  = t0 + tt;
        const long tn = (tt + 2 < TPW) ? (t + 2) : t;
        f32x4 xn0 = x4[tn * 16 + i];
        f32x4 xn1 = x4[(tn + 1) * 16 + i];

        f32x4 z0 = tile_eval(xv0, A1f, A2f, Cinit, isg1);
        f32x4 z1 = tile_eval(xv1, A1f, A2f, Cinit, isg1);

        if (g == 0) {
            out4[t * 16 + i]       = z0;
            out4[(t + 1) * 16 + i] = z1;
        }
        xv0 = xn0;
        xv1 = xn1;
    }
}

extern "C" void kernel_launch(void* const* d_in, const int* in_sizes, int n_in,
                              void* d_out, int out_size, void* d_ws, size_t ws_size,
                              hipStream_t stream) {
    const float* x  = (const float*)d_in[0];
    const float* W1 = (const float*)d_in[1];
    const float* b1 = (const float*)d_in[2];
    const float* W2 = (const float*)d_in[3];
    const float* b2 = (const float*)d_in[4];
    float* out = (float*)d_out;
    uint*  ws  = (uint*)d_ws;

    prep_kernel<<<1, 256, 0, stream>>>(W1, b1, W2, b2, ws);
    mlp_kernel<<<NBLK, TPB, 0, stream>>>(x, ws, out);
}

// Round 8
// 157.745 us; speedup vs baseline: 1.1719x; 1.0404x over previous
//
#include <hip/hip_runtime.h>
#include <math.h>

// Net_90434831385322: z = A + span*sigmoid(relu((x-A)/span @ W1 + b1) @ W2 + b2)
// BATCH=4194304, OBS=4, HID=64, ACT=4, all fp32.
//
// R10b: identical to R10 (container infra failure, not a kernel result).
//      Cut the marshaling VALU. R9 closed the model (75us = 296 issue-cyc/tile
//      + stalls; VALU-issue-bound). Changes:
//      (1) 4-tile merged epilogue: per 4-tile group, g0 lanes ds_write their
//          C rows (acts) to 1KB LDS, all 64 lanes ds_read back merged ->
//          ONE epilogue pass + ONE fully-coalesced store per 4 tiles.
//          Epilogue+store: ~83 -> ~22 issue-cyc/tile (trans 8cyc/op, 8->2/tile).
//      (2) b1 moved from MFMA K-slots to L1 C-init (b1i[T] = b1'[16T+4g+r],
//          per-lane constant, fp32-EXACT). B1 becomes {xhi,xhi,xlo,xlo} in
//          every lane -> no cndmasks; A1 g1 upper half = 0.
//      (3) 4 independent tile cores per group (ILP), group-ahead x prefetch.
//      Static: ~232 issue-cyc/tile (was ~296). Layout (verified R6-R9):
//      swapped L1, L2 K-order == L1 C-order, 3-term bf16 split, exp2 fold.

#define BATCH   4194304
#define HID     64
#define TPB     256
#define TILES   (BATCH / 16)              // 262144 16-row tiles
#define TPW     8                         // tiles per wave (2 groups of 4)
#define NWAVES  (TILES / TPW)             // 32768 waves
#define NBLK    (NWAVES / 4)              // 8192 blocks (4 waves each)

typedef float  f32x4  __attribute__((ext_vector_type(4)));
typedef short  bf16x8 __attribute__((ext_vector_type(8)));
typedef unsigned int uint;
typedef uint   u32x4  __attribute__((ext_vector_type(4)));

// ws layout (dwords):
//   [0    .. 1023]  A1 frags: [T=0..3][lane][4 dw]; g0:{W1hi|W1hi}, g1:{W1lo|0}, g2,g3:0
//   [1024 .. 2047]  A2 frags: [f=0..3][lane][4 dw]; f0,f1=W2hi'' chunks; f2,f3=W2lo''
//                   (W2'' = -log2e * W2)
//   [2048 .. 2051]  b2'' = -log2e * b2 (fp32 bits)
//   [2056 .. 2119]  b1' fp32 (input-scale-folded), hid-indexed
#define WS_A1   0
#define WS_A2   1024
#define WS_B2   2048
#define WS_B1   2056

// fp32 -> bf16 RNE (prep side)
static __device__ __forceinline__ uint b16(float f) {
    uint u = __float_as_uint(f);
    return (u + 0x7FFFu + ((u >> 16) & 1u)) >> 16;
}
static __device__ __forceinline__ float b16f(uint h) {
    return __uint_as_float(h << 16);
}

// packed f32x2 -> bf16x2 (RNE), dst = {bf16(b), bf16(a)}
static __device__ __forceinline__ uint cvtpk(float a, float b) {
    uint r;
    asm("v_cvt_pk_bf16_f32 %0, %1, %2" : "=v"(r) : "v"(a), "v"(b));
    return r;
}

// packed truncated-bf16 pair from two f32: {hi16(b), hi16(a)} -- one v_perm_b32
#define PERM_SEL 0x07060302u
static __device__ __forceinline__ uint trunc_pk(float a, float b) {
    return __builtin_amdgcn_perm(__float_as_uint(b), __float_as_uint(a), PERM_SEL);
}

// deterministic raw 2^x
static __device__ __forceinline__ float exp2_fast(float a) {
    float r;
    asm("v_exp_f32 %0, %1" : "=v"(r) : "v"(a));
    return r;
}

__global__ __launch_bounds__(256)
void prep_kernel(const float* __restrict__ W1, const float* __restrict__ b1,
                 const float* __restrict__ W2, const float* __restrict__ b2,
                 uint* __restrict__ ws) {
    const float A_[4] = {0.001f, 0.02f, 0.05f, 0.001f};
    const float S_[4] = {0.003f, 0.03f, 0.15f, 0.003f};   // span = B - A
    const float NL2E  = -1.442695040888963f;              // -log2(e)
    const int tid = threadIdx.x;
    const int w = tid >> 6;               // 0..3: selects T (A1) and f (A2)
    const int l = tid & 63;               // lane 0..63
    const int g = l >> 4;                 // k-group
    const int i = l & 15;                 // A free index (hid-in-tile / act)

    // ---- A1 frag for T=w: A1[row=hid=16T+i, k=8g+j] ----
    // B1 (runtime) = {xhi0-3, xlo0-3} identical in all lanes, so per g the
    // 8 k-slots see {xhi(4), xlo(4)}:
    //   g0: k0-3 = W1hi (x xhi), k4-7 = W1hi (x xlo)
    //   g1: k8-11 = W1lo (x xhi), k12-15 = 0 (drops W1lo*xlo, ~2^-18 rel)
    //   g2,g3: 0.  b1 is NOT here (moved to L1 C-init, exact fp32).
    {
        int hid = 16 * w + i;
        uint s8[8] = {0, 0, 0, 0, 0, 0, 0, 0};
        if (g < 2) {
            #pragma unroll
            for (int k = 0; k < 4; ++k) {
                float wv  = W1[k * HID + hid] / S_[k];     // fold input scale
                uint  whi = b16(wv);
                if (g == 0) { s8[k] = whi; s8[4 + k] = whi; }
                else        { s8[k] = b16(wv - b16f(whi)); }
            }
        }
        #pragma unroll
        for (int d = 0; d < 4; ++d)
            ws[WS_A1 + (w * 64 + l) * 4 + d] = (s8[2 * d + 1] << 16) | (s8[2 * d] & 0xFFFFu);
    }

    // ---- A2 frag for f=w: A2[row=act=i, k=8g+j], hid(k)=32c+16*(j>>2)+4g+(j&3) ----
    // W2'' = -log2e * W2  (so C2 = -y*log2e and sigmoid = 1/(1+exp2(C2)))
    {
        int  c  = w & 1;
        bool lo = (w >= 2);
        uint s8[8];
        #pragma unroll
        for (int j = 0; j < 8; ++j) {
            int hid = 32 * c + 16 * (j >> 2) + 4 * g + (j & 3);
            uint v = 0;
            if (i < 4) {
                float wv = W2[hid * 4 + i] * NL2E;
                uint  wh = b16(wv);
                v = lo ? b16(wv - b16f(wh)) : wh;
            }
            s8[j] = v;
        }
        #pragma unroll
        for (int d = 0; d < 4; ++d)
            ws[WS_A2 + (w * 64 + l) * 4 + d] = (s8[2 * d + 1] << 16) | (s8[2 * d] & 0xFFFFu);
    }

    if (tid < 4) ws[WS_B2 + tid] = __float_as_uint(b2[tid] * NL2E);

    // ---- b1' fp32 table (exact; input-scale folded) ----
    if (tid < HID) {
        float bb = b1[tid];
        #pragma unroll
        for (int k = 0; k < 4; ++k) bb -= (A_[k] / S_[k]) * W1[k * HID + tid];
        ws[WS_B1 + tid] = __float_as_uint(bb);
    }
}

// One 16-row tile core: x -> C (= -log2e * y, acts in rows 0-3 / g0 lanes).
static __device__ __forceinline__ f32x4 tile_core(f32x4 xv,
                                                  const bf16x8* __restrict__ A1f,
                                                  const bf16x8* __restrict__ A2f,
                                                  const f32x4* __restrict__ b1i,
                                                  f32x4 Cinit) {
    // ---- B1 (x split, truncation-hi): identical content in every lane ----
    uint xhi01 = trunc_pk(xv.x, xv.y);
    uint xhi23 = trunc_pk(xv.z, xv.w);
    float h0 = __uint_as_float(__float_as_uint(xv.x) & 0xFFFF0000u);
    float h1 = __uint_as_float(__float_as_uint(xv.y) & 0xFFFF0000u);
    float h2 = __uint_as_float(__float_as_uint(xv.z) & 0xFFFF0000u);
    float h3 = __uint_as_float(__float_as_uint(xv.w) & 0xFFFF0000u);
    uint xlo01 = cvtpk(xv.x - h0, xv.y - h1);
    uint xlo23 = cvtpk(xv.z - h2, xv.w - h3);
    u32x4 bw = {xhi01, xhi23, xlo01, xlo23};
    bf16x8 B1 = __builtin_bit_cast(bf16x8, bw);

    // ---- layer 1: h^T[hid, batch], b1' exact via C-init ----
    f32x4 h[4];
    #pragma unroll
    for (int T = 0; T < 4; ++T)
        h[T] = __builtin_amdgcn_mfma_f32_16x16x32_bf16(A1f[T], B1, b1i[T], 0, 0, 0);

    // ---- relu + truncation split of h ----
    uint Whi[8], Wlo[8];
    #pragma unroll
    for (int T = 0; T < 4; ++T) {
        float r0 = fmaxf(h[T][0], 0.f), r1 = fmaxf(h[T][1], 0.f);
        float r2 = fmaxf(h[T][2], 0.f), r3 = fmaxf(h[T][3], 0.f);
        Whi[2 * T]     = trunc_pk(r0, r1);
        Whi[2 * T + 1] = trunc_pk(r2, r3);
        float f0 = __uint_as_float(__float_as_uint(r0) & 0xFFFF0000u);
        float f1 = __uint_as_float(__float_as_uint(r1) & 0xFFFF0000u);
        float f2 = __uint_as_float(__float_as_uint(r2) & 0xFFFF0000u);
        float f3 = __uint_as_float(__float_as_uint(r3) & 0xFFFF0000u);
        Wlo[2 * T]     = cvtpk(r0 - f0, r1 - f1);
        Wlo[2 * T + 1] = cvtpk(r2 - f2, r3 - f3);
    }
    u32x4 bh0 = {Whi[0], Whi[1], Whi[2], Whi[3]};
    u32x4 bh1 = {Whi[4], Whi[5], Whi[6], Whi[7]};
    u32x4 bl0 = {Wlo[0], Wlo[1], Wlo[2], Wlo[3]};
    u32x4 bl1 = {Wlo[4], Wlo[5], Wlo[6], Wlo[7]};
    bf16x8 Bhi0 = __builtin_bit_cast(bf16x8, bh0);
    bf16x8 Bhi1 = __builtin_bit_cast(bf16x8, bh1);
    bf16x8 Blo0 = __builtin_bit_cast(bf16x8, bl0);
    bf16x8 Blo1 = __builtin_bit_cast(bf16x8, bl1);

    // ---- layer 2: two independent 3-MFMA chains ----
    f32x4 Ca = Cinit;                     // carries b2''
    f32x4 Cb = {0.f, 0.f, 0.f, 0.f};
    Ca = __builtin_amdgcn_mfma_f32_16x16x32_bf16(A2f[0], Bhi0, Ca, 0, 0, 0);
    Cb = __builtin_amdgcn_mfma_f32_16x16x32_bf16(A2f[1], Bhi1, Cb, 0, 0, 0);
    Ca = __builtin_amdgcn_mfma_f32_16x16x32_bf16(A2f[0], Blo0, Ca, 0, 0, 0);
    Cb = __builtin_amdgcn_mfma_f32_16x16x32_bf16(A2f[1], Blo1, Cb, 0, 0, 0);
    Ca = __builtin_amdgcn_mfma_f32_16x16x32_bf16(A2f[2], Bhi0, Ca, 0, 0, 0);
    Cb = __builtin_amdgcn_mfma_f32_16x16x32_bf16(A2f[3], Bhi1, Cb, 0, 0, 0);
    return Ca + Cb;                       // C = -log2e*y
}

__global__ __launch_bounds__(TPB, 2)
void mlp_kernel(const float* __restrict__ x, const uint* __restrict__ ws,
                float* __restrict__ out) {
    const int lane = threadIdx.x & 63;
    const int wv   = threadIdx.x >> 6;
    const int g    = lane >> 4;
    const int i    = lane & 15;

    // 4-tile C merge buffer: [wave][tile*16 + col] (write by g0 lanes),
    // read back linearly as [wave][lane]. Per-wave buffer: wave-synchronous,
    // no __syncthreads needed (compiler inserts the lgkmcnt dep wait).
    __shared__ f32x4 sC[4][64];

    const f32x4* __restrict__ x4   = (const f32x4*)x;
    f32x4* __restrict__       out4 = (f32x4*)out;
    const u32x4* __restrict__ wsv  = (const u32x4*)ws;

    // Loop-invariant: weight frags, b1-init (per-lane rows 16T+4g+r), b2''.
    bf16x8 A1f[4], A2f[4];
    #pragma unroll
    for (int T = 0; T < 4; ++T) A1f[T] = __builtin_bit_cast(bf16x8, wsv[(WS_A1 / 4) + T * 64 + lane]);
    #pragma unroll
    for (int f = 0; f < 4; ++f) A2f[f] = __builtin_bit_cast(bf16x8, wsv[(WS_A2 / 4) + f * 64 + lane]);
    const f32x4* b1p = (const f32x4*)(ws + WS_B1);
    f32x4 b1i[4];
    #pragma unroll
    for (int T = 0; T < 4; ++T) b1i[T] = b1p[T * 4 + g];
    const float* wsf = (const float*)ws;
    f32x4 Cinit = {wsf[WS_B2], wsf[WS_B2 + 1], wsf[WS_B2 + 2], wsf[WS_B2 + 3]};

    const float LA[4] = {0.001f, 0.02f, 0.05f, 0.001f};
    const float LS[4] = {0.003f, 0.03f, 0.15f, 0.003f};

    const long wave_id = (long)blockIdx.x * 4 + wv;
    const long t0      = wave_id * TPW;

    // Group-ahead x prefetch (all lanes load their col i; 4x g-redundant,
    // L2-served, VMEM pipe is idle anyway).
    f32x4 xc[4], xn[4];
    #pragma unroll
    for (int q = 0; q < 4; ++q) xc[q] = x4[(t0 + q) * 16 + i];

    #pragma unroll
    for (int grp = 0; grp < TPW / 4; ++grp) {
        const long tg = t0 + grp * 4;
        const long tn = (grp + 1 < TPW / 4) ? tg + 4 : tg;
        #pragma unroll
        for (int q = 0; q < 4; ++q) xn[q] = x4[(tn + q) * 16 + i];

        // 4 independent tile cores; g0 lanes park their act-rows in LDS.
        #pragma unroll
        for (int q = 0; q < 4; ++q) {
            f32x4 C = tile_core(xc[q], A1f, A2f, b1i, Cinit);
            if (g == 0) sC[wv][q * 16 + i] = C;
        }

        // Merged epilogue: lane (g,i) handles tile tg+g, col i.
        f32x4 M = sC[wv][lane];
        f32x4 z;
        #pragma unroll
        for (int c = 0; c < 4; ++c) {
            float e = exp2_fast(M[c]);
            z[c] = fmaf(LS[c], __builtin_amdgcn_rcpf(1.0f + e), LA[c]);
        }
        out4[tg * 16 + lane] = z;         // 64 lanes x 16B, fully coalesced

        #pragma unroll
        for (int q = 0; q < 4; ++q) xc[q] = xn[q];
    }
}

extern "C" void kernel_launch(void* const* d_in, const int* in_sizes, int n_in,
                              void* d_out, int out_size, void* d_ws, size_t ws_size,
                              hipStream_t stream) {
    const float* x  = (const float*)d_in[0];
    const float* W1 = (const float*)d_in[1];
    const float* b1 = (const float*)d_in[2];
    const float* W2 = (const float*)d_in[3];
    const float* b2 = (const float*)d_in[4];
    float* out = (float*)d_out;
    uint*  ws  = (uint*)d_ws;

    prep_kernel<<<1, 256, 0, stream>>>(W1, b1, W2, b2, ws);
    mlp_kernel<<<NBLK, TPB, 0, stream>>>(x, ws, out);
}

// Round 9
// 155.986 us; speedup vs baseline: 1.1852x; 1.0113x over previous
//
#include <hip/hip_runtime.h>
#include <math.h>

// Net_90434831385322: z = A + span*sigmoid(relu((x-A)/span @ W1 + b1) @ W2 + b2)
// BATCH=4194304, OBS=4, HID=64, ACT=4, all fp32.
//
// R11: occupancy, not instructions. R10 matched its model (68.5us; MfmaUtil 25,
//      instr cut landed) but Occupancy fell 53->36% (4-deep xc/xn prefetch =
//      32 live VGPRs) and issue efficiency dropped to 3.6 cyc/instr at ~2.9
//      waves/SIMD. The 3-term split is accuracy-mandatory (dropping any term
//      -> z-err 4e-3..1e-2), so ~85 VALU/tile is the algorithmic floor;
//      remaining ~20us is idle-issue recovery via residency.
//      Changes vs R10:
//       (1) xn[4] prefetch gone; xc[4] loaded at group start (unrolled group
//           loop lets the scheduler hoist next-group loads; x is L3-resident).
//       (2) __launch_bounds__(256, 4): trimmed live set (~110-125) fits the
//           128-reg budget -> 4 waves/SIMD without AGPR parking.
//       (3) TPW 16 (4096 blocks): halves per-block frag-load prologues.
//      Layout (verified R6-R10): swapped L1, L2 K-order == L1 C-order, 3-term
//      bf16 split, b1 exact via L1 C-init, exp2 fold, 4-tile LDS epilogue.

#define BATCH   4194304
#define HID     64
#define TPB     256
#define TILES   (BATCH / 16)              // 262144 16-row tiles
#define TPW     16                        // tiles per wave (4 groups of 4)
#define NWAVES  (TILES / TPW)             // 16384 waves
#define NBLK    (NWAVES / 4)              // 4096 blocks (4 waves each)

typedef float  f32x4  __attribute__((ext_vector_type(4)));
typedef short  bf16x8 __attribute__((ext_vector_type(8)));
typedef unsigned int uint;
typedef uint   u32x4  __attribute__((ext_vector_type(4)));

// ws layout (dwords):
//   [0    .. 1023]  A1 frags: [T=0..3][lane][4 dw]; g0:{W1hi|W1hi}, g1:{W1lo|0}, g2,g3:0
//   [1024 .. 2047]  A2 frags: [f=0..3][lane][4 dw]; f0,f1=W2hi'' chunks; f2,f3=W2lo''
//                   (W2'' = -log2e * W2)
//   [2048 .. 2051]  b2'' = -log2e * b2 (fp32 bits)
//   [2056 .. 2119]  b1' fp32 (input-scale-folded), hid-indexed
#define WS_A1   0
#define WS_A2   1024
#define WS_B2   2048
#define WS_B1   2056

// fp32 -> bf16 RNE (prep side)
static __device__ __forceinline__ uint b16(float f) {
    uint u = __float_as_uint(f);
    return (u + 0x7FFFu + ((u >> 16) & 1u)) >> 16;
}
static __device__ __forceinline__ float b16f(uint h) {
    return __uint_as_float(h << 16);
}

// packed f32x2 -> bf16x2 (RNE), dst = {bf16(b), bf16(a)}
static __device__ __forceinline__ uint cvtpk(float a, float b) {
    uint r;
    asm("v_cvt_pk_bf16_f32 %0, %1, %2" : "=v"(r) : "v"(a), "v"(b));
    return r;
}

// packed truncated-bf16 pair from two f32: {hi16(b), hi16(a)} -- one v_perm_b32
#define PERM_SEL 0x07060302u
static __device__ __forceinline__ uint trunc_pk(float a, float b) {
    return __builtin_amdgcn_perm(__float_as_uint(b), __float_as_uint(a), PERM_SEL);
}

// deterministic raw 2^x
static __device__ __forceinline__ float exp2_fast(float a) {
    float r;
    asm("v_exp_f32 %0, %1" : "=v"(r) : "v"(a));
    return r;
}

__global__ __launch_bounds__(256)
void prep_kernel(const float* __restrict__ W1, const float* __restrict__ b1,
                 const float* __restrict__ W2, const float* __restrict__ b2,
                 uint* __restrict__ ws) {
    const float A_[4] = {0.001f, 0.02f, 0.05f, 0.001f};
    const float S_[4] = {0.003f, 0.03f, 0.15f, 0.003f};   // span = B - A
    const float NL2E  = -1.442695040888963f;              // -log2(e)
    const int tid = threadIdx.x;
    const int w = tid >> 6;               // 0..3: selects T (A1) and f (A2)
    const int l = tid & 63;               // lane 0..63
    const int g = l >> 4;                 // k-group
    const int i = l & 15;                 // A free index (hid-in-tile / act)

    // ---- A1 frag for T=w: A1[row=hid=16T+i, k=8g+j] ----
    //   g0: k0-3 = W1hi (x xhi), k4-7 = W1hi (x xlo)
    //   g1: k8-11 = W1lo (x xhi), k12-15 = 0
    //   g2,g3: 0.  b1 is in the L1 C-init (exact fp32).
    {
        int hid = 16 * w + i;
        uint s8[8] = {0, 0, 0, 0, 0, 0, 0, 0};
        if (g < 2) {
            #pragma unroll
            for (int k = 0; k < 4; ++k) {
                float wv  = W1[k * HID + hid] / S_[k];     // fold input scale
                uint  whi = b16(wv);
                if (g == 0) { s8[k] = whi; s8[4 + k] = whi; }
                else        { s8[k] = b16(wv - b16f(whi)); }
            }
        }
        #pragma unroll
        for (int d = 0; d < 4; ++d)
            ws[WS_A1 + (w * 64 + l) * 4 + d] = (s8[2 * d + 1] << 16) | (s8[2 * d] & 0xFFFFu);
    }

    // ---- A2 frag for f=w: A2[row=act=i, k=8g+j], hid(k)=32c+16*(j>>2)+4g+(j&3) ----
    // W2'' = -log2e * W2  (so C2 = -y*log2e and sigmoid = 1/(1+exp2(C2)))
    {
        int  c  = w & 1;
        bool lo = (w >= 2);
        uint s8[8];
        #pragma unroll
        for (int j = 0; j < 8; ++j) {
            int hid = 32 * c + 16 * (j >> 2) + 4 * g + (j & 3);
            uint v = 0;
            if (i < 4) {
                float wv = W2[hid * 4 + i] * NL2E;
                uint  wh = b16(wv);
                v = lo ? b16(wv - b16f(wh)) : wh;
            }
            s8[j] = v;
        }
        #pragma unroll
        for (int d = 0; d < 4; ++d)
            ws[WS_A2 + (w * 64 + l) * 4 + d] = (s8[2 * d + 1] << 16) | (s8[2 * d] & 0xFFFFu);
    }

    if (tid < 4) ws[WS_B2 + tid] = __float_as_uint(b2[tid] * NL2E);

    // ---- b1' fp32 table (exact; input-scale folded) ----
    if (tid < HID) {
        float bb = b1[tid];
        #pragma unroll
        for (int k = 0; k < 4; ++k) bb -= (A_[k] / S_[k]) * W1[k * HID + tid];
        ws[WS_B1 + tid] = __float_as_uint(bb);
    }
}

// One 16-row tile core: x -> C (= -log2e * y, acts in rows 0-3 / g0 lanes).
static __device__ __forceinline__ f32x4 tile_core(f32x4 xv,
                                                  const bf16x8* __restrict__ A1f,
                                                  const bf16x8* __restrict__ A2f,
                                                  const f32x4* __restrict__ b1i,
                                                  f32x4 Cinit) {
    // ---- B1 (x split, truncation-hi): identical content in every lane ----
    uint xhi01 = trunc_pk(xv.x, xv.y);
    uint xhi23 = trunc_pk(xv.z, xv.w);
    float h0 = __uint_as_float(__float_as_uint(xv.x) & 0xFFFF0000u);
    float h1 = __uint_as_float(__float_as_uint(xv.y) & 0xFFFF0000u);
    float h2 = __uint_as_float(__float_as_uint(xv.z) & 0xFFFF0000u);
    float h3 = __uint_as_float(__float_as_uint(xv.w) & 0xFFFF0000u);
    uint xlo01 = cvtpk(xv.x - h0, xv.y - h1);
    uint xlo23 = cvtpk(xv.z - h2, xv.w - h3);
    u32x4 bw = {xhi01, xhi23, xlo01, xlo23};
    bf16x8 B1 = __builtin_bit_cast(bf16x8, bw);

    // ---- layer 1: h^T[hid, batch], b1' exact via C-init ----
    f32x4 h[4];
    #pragma unroll
    for (int T = 0; T < 4; ++T)
        h[T] = __builtin_amdgcn_mfma_f32_16x16x32_bf16(A1f[T], B1, b1i[T], 0, 0, 0);

    // ---- relu + truncation split of h ----
    uint Whi[8], Wlo[8];
    #pragma unroll
    for (int T = 0; T < 4; ++T) {
        float r0 = fmaxf(h[T][0], 0.f), r1 = fmaxf(h[T][1], 0.f);
        float r2 = fmaxf(h[T][2], 0.f), r3 = fmaxf(h[T][3], 0.f);
        Whi[2 * T]     = trunc_pk(r0, r1);
        Whi[2 * T + 1] = trunc_pk(r2, r3);
        float f0 = __uint_as_float(__float_as_uint(r0) & 0xFFFF0000u);
        float f1 = __uint_as_float(__float_as_uint(r1) & 0xFFFF0000u);
        float f2 = __uint_as_float(__float_as_uint(r2) & 0xFFFF0000u);
        float f3 = __uint_as_float(__float_as_uint(r3) & 0xFFFF0000u);
        Wlo[2 * T]     = cvtpk(r0 - f0, r1 - f1);
        Wlo[2 * T + 1] = cvtpk(r2 - f2, r3 - f3);
    }
    u32x4 bh0 = {Whi[0], Whi[1], Whi[2], Whi[3]};
    u32x4 bh1 = {Whi[4], Whi[5], Whi[6], Whi[7]};
    u32x4 bl0 = {Wlo[0], Wlo[1], Wlo[2], Wlo[3]};
    u32x4 bl1 = {Wlo[4], Wlo[5], Wlo[6], Wlo[7]};
    bf16x8 Bhi0 = __builtin_bit_cast(bf16x8, bh0);
    bf16x8 Bhi1 = __builtin_bit_cast(bf16x8, bh1);
    bf16x8 Blo0 = __builtin_bit_cast(bf16x8, bl0);
    bf16x8 Blo1 = __builtin_bit_cast(bf16x8, bl1);

    // ---- layer 2: two independent 3-MFMA chains ----
    f32x4 Ca = Cinit;                     // carries b2''
    f32x4 Cb = {0.f, 0.f, 0.f, 0.f};
    Ca = __builtin_amdgcn_mfma_f32_16x16x32_bf16(A2f[0], Bhi0, Ca, 0, 0, 0);
    Cb = __builtin_amdgcn_mfma_f32_16x16x32_bf16(A2f[1], Bhi1, Cb, 0, 0, 0);
    Ca = __builtin_amdgcn_mfma_f32_16x16x32_bf16(A2f[0], Blo0, Ca, 0, 0, 0);
    Cb = __builtin_amdgcn_mfma_f32_16x16x32_bf16(A2f[1], Blo1, Cb, 0, 0, 0);
    Ca = __builtin_amdgcn_mfma_f32_16x16x32_bf16(A2f[2], Bhi0, Ca, 0, 0, 0);
    Cb = __builtin_amdgcn_mfma_f32_16x16x32_bf16(A2f[3], Bhi1, Cb, 0, 0, 0);
    return Ca + Cb;                       // C = -log2e*y
}

__global__ __launch_bounds__(TPB, 4)
void mlp_kernel(const float* __restrict__ x, const uint* __restrict__ ws,
                float* __restrict__ out) {
    const int lane = threadIdx.x & 63;
    const int wv   = threadIdx.x >> 6;
    const int g    = lane >> 4;
    const int i    = lane & 15;

    // 4-tile C merge buffer: [wave][tile*16 + col] (write by g0 lanes),
    // read back linearly as [wave][lane]. Per-wave buffer: wave-synchronous,
    // no __syncthreads needed (compiler inserts the lgkmcnt dep wait).
    __shared__ f32x4 sC[4][64];

    const f32x4* __restrict__ x4   = (const f32x4*)x;
    f32x4* __restrict__       out4 = (f32x4*)out;
    const u32x4* __restrict__ wsv  = (const u32x4*)ws;

    // Loop-invariant: weight frags, b1-init (per-lane rows 16T+4g+r), b2''.
    bf16x8 A1f[4], A2f[4];
    #pragma unroll
    for (int T = 0; T < 4; ++T) A1f[T] = __builtin_bit_cast(bf16x8, wsv[(WS_A1 / 4) + T * 64 + lane]);
    #pragma unroll
    for (int f = 0; f < 4; ++f) A2f[f] = __builtin_bit_cast(bf16x8, wsv[(WS_A2 / 4) + f * 64 + lane]);
    const f32x4* b1p = (const f32x4*)(ws + WS_B1);
    f32x4 b1i[4];
    #pragma unroll
    for (int T = 0; T < 4; ++T) b1i[T] = b1p[T * 4 + g];
    const float* wsf = (const float*)ws;
    f32x4 Cinit = {wsf[WS_B2], wsf[WS_B2 + 1], wsf[WS_B2 + 2], wsf[WS_B2 + 3]};

    const float LA[4] = {0.001f, 0.02f, 0.05f, 0.001f};
    const float LS[4] = {0.003f, 0.03f, 0.15f, 0.003f};

    const long wave_id = (long)blockIdx.x * 4 + wv;
    const long t0      = wave_id * TPW;

    #pragma unroll
    for (int grp = 0; grp < TPW / 4; ++grp) {
        const long tg = t0 + grp * 4;

        // Group x loads (L3-resident; unrolled loop lets the scheduler hoist
        // these into the previous group's compute).
        f32x4 xc[4];
        #pragma unroll
        for (int q = 0; q < 4; ++q) xc[q] = x4[(tg + q) * 16 + i];

        // 4 independent tile cores; g0 lanes park their act-rows in LDS.
        #pragma unroll
        for (int q = 0; q < 4; ++q) {
            f32x4 C = tile_core(xc[q], A1f, A2f, b1i, Cinit);
            if (g == 0) sC[wv][q * 16 + i] = C;
        }

        // Merged epilogue: lane (g,i) handles tile tg+g, col i.
        f32x4 M = sC[wv][lane];
        f32x4 z;
        #pragma unroll
        for (int c = 0; c < 4; ++c) {
            float e = exp2_fast(M[c]);
            z[c] = fmaf(LS[c], __builtin_amdgcn_rcpf(1.0f + e), LA[c]);
        }
        out4[tg * 16 + lane] = z;         // 64 lanes x 16B, fully coalesced
    }
}

extern "C" void kernel_launch(void* const* d_in, const int* in_sizes, int n_in,
                              void* d_out, int out_size, void* d_ws, size_t ws_size,
                              hipStream_t stream) {
    const float* x  = (const float*)d_in[0];
    const float* W1 = (const float*)d_in[1];
    const float* b1 = (const float*)d_in[2];
    const float* W2 = (const float*)d_in[3];
    const float* b2 = (const float*)d_in[4];
    float* out = (float*)d_out;
    uint*  ws  = (uint*)d_ws;

    prep_kernel<<<1, 256, 0, stream>>>(W1, b1, W2, b2, ws);
    mlp_kernel<<<NBLK, TPB, 0, stream>>>(x, ws, out);
}